// Round 12
// baseline (144.049 us; speedup 1.0000x reference)
//
#include <hip/hip_runtime.h>

// ---------------------------------------------------------------------------
// 2-layer TransformerConv factored through the 2-dim feature spaces.
// Round 12: proj_k was LDS-instruction-bound (14 ds_read_b128/node, LDS pipe
// is per-CU => ~27us hidden cost). Now each 8-lane group owns 4 nodes and
// re-uses every weight read 4x => 3.5 ds_read/node (~7us). Rest unchanged.
// ---------------------------------------------------------------------------

#define R_LOG2   8
#define R_DSTS   256            // dsts per bucket
#define BE       4096           // edges per partition block
#define MAXNB    512            // supports N <= 131072
#define CAPB     4608           // slots per bucket (mean 4096, sd 64 -> 8 sigma)
#define S_SLICES 4              // edge slices per bucket
#define RSQRT2   0.70710678118654752f

// 9 reduction coefficients for the layer-1 bilinear attention form:
// q1(d).k1(s) = xd^T M xs + u.xd + w.xs + c   (before 1/16 scale)
__global__ void coeff_k(const float* __restrict__ Wq1, const float* __restrict__ bq1,
                        const float* __restrict__ Wk1, const float* __restrict__ bk1,
                        float* __restrict__ coeff) {
    __shared__ float part[4][9];
    int c = threadIdx.x;  // 256 threads
    float wq0 = Wq1[c], wq1 = Wq1[256 + c];
    float wk0 = Wk1[c], wk1 = Wk1[256 + c];
    float bq = bq1[c], bk = bk1[c];
    float vals[9] = { wq0 * wk0, wq0 * wk1, wq1 * wk0, wq1 * wk1,
                      wq0 * bk,  wq1 * bk,  bq * wk0,  bq * wk1,  bq * bk };
    int lane = c & 63, w = c >> 6;
#pragma unroll
    for (int i = 0; i < 9; ++i) {
        float v = vals[i];
#pragma unroll
        for (int o = 32; o > 0; o >>= 1) v += __shfl_xor(v, o);
        if (lane == 0) part[w][i] = v;
    }
    __syncthreads();
    if (c < 9) coeff[c] = part[0][c] + part[1][c] + part[2][c] + part[3][c];
}

// Single-pass locally-sorted scatter: LDS histogram -> in-block scan ->
// global segment reservation (1 atomicAdd per touched bucket) -> rank &
// stage in bucket order -> ordered coalesced segment writes.
__global__ __launch_bounds__(256) void scatter1_k(
        const int* __restrict__ src, const int* __restrict__ dst,
        int* __restrict__ cnt, int* __restrict__ recs, int NB, int E) {
    __shared__ int hist[MAXNB];
    __shared__ int lofs[MAXNB];
    __shared__ int gbase[MAXNB];
    __shared__ int stage[BE];
    __shared__ unsigned short sbkt[BE];
    __shared__ int wsum[4];
    int t = threadIdx.x;
    for (int i = t; i < NB; i += 256) hist[i] = 0;
    __syncthreads();

    int base = blockIdx.x * BE;
    int nloc = E - base; if (nloc > BE) nloc = BE;
    int nv = nloc >> 2;
    const int4* d4 = (const int4*)(dst + base);
    const int4* s4 = (const int4*)(src + base);

    // pass 1: local histogram
    for (int i = t; i < nv; i += 256) {
        int4 v = d4[i];
        atomicAdd(&hist[v.x >> R_LOG2], 1);
        atomicAdd(&hist[v.y >> R_LOG2], 1);
        atomicAdd(&hist[v.z >> R_LOG2], 1);
        atomicAdd(&hist[v.w >> R_LOG2], 1);
    }
    for (int i = (nv << 2) + t; i < nloc; i += 256)
        atomicAdd(&hist[dst[base + i] >> R_LOG2], 1);
    __syncthreads();

    // in-block exclusive scan hist -> lofs (2 entries per thread, NB<=512)
    {
        int i0 = 2 * t, i1 = 2 * t + 1;
        int a = (i0 < NB) ? hist[i0] : 0;
        int b = (i1 < NB) ? hist[i1] : 0;
        int s = a + b;
        int lane = t & 63, w = t >> 6;
        int incl = s;
#pragma unroll
        for (int o = 1; o < 64; o <<= 1) {
            int u = __shfl_up(incl, o);
            if (lane >= o) incl += u;
        }
        if (lane == 63) wsum[w] = incl;
        __syncthreads();
        int ex = incl - s;
        for (int j = 0; j < w; ++j) ex += wsum[j];
        if (i0 < NB) lofs[i0] = ex;
        if (i1 < NB) lofs[i1] = ex + a;
    }
    __syncthreads();

    // reserve a contiguous segment in each touched bucket, reset hist
    for (int b = t; b < NB; b += 256) {
        int h = hist[b];
        int start = h ? atomicAdd(&cnt[b], h) : 0;
        gbase[b] = b * CAPB + start - lofs[b];
        hist[b] = 0;
    }
    __syncthreads();

    // pass 2: rank & stage in bucket-sorted order
    for (int i = t; i < nv; i += 256) {
        int4 dv = d4[i];
        int4 sv = s4[i];
        int d, b, r, p;
        d = dv.x; b = d >> R_LOG2; r = atomicAdd(&hist[b], 1); p = lofs[b] + r;
        stage[p] = sv.x | ((d & (R_DSTS - 1)) << 17); sbkt[p] = (unsigned short)b;
        d = dv.y; b = d >> R_LOG2; r = atomicAdd(&hist[b], 1); p = lofs[b] + r;
        stage[p] = sv.y | ((d & (R_DSTS - 1)) << 17); sbkt[p] = (unsigned short)b;
        d = dv.z; b = d >> R_LOG2; r = atomicAdd(&hist[b], 1); p = lofs[b] + r;
        stage[p] = sv.z | ((d & (R_DSTS - 1)) << 17); sbkt[p] = (unsigned short)b;
        d = dv.w; b = d >> R_LOG2; r = atomicAdd(&hist[b], 1); p = lofs[b] + r;
        stage[p] = sv.w | ((d & (R_DSTS - 1)) << 17); sbkt[p] = (unsigned short)b;
    }
    for (int i = (nv << 2) + t; i < nloc; i += 256) {
        int d = dst[base + i];
        int b = d >> R_LOG2;
        int r = atomicAdd(&hist[b], 1);
        int p = lofs[b] + r;
        stage[p] = src[base + i] | ((d & (R_DSTS - 1)) << 17);
        sbkt[p] = (unsigned short)b;
    }
    __syncthreads();

    // pass 3: ordered write — consecutive i -> consecutive addresses per
    // segment; bound-checked against the bucket's fixed capacity.
    for (int i = t; i < nloc; i += 256) {
        int bk = sbkt[i];
        int p = gbase[bk] + i;
        if (p < (bk + 1) * CAPB) recs[p] = stage[i];
    }
}

// Layer-1 edge reduce, one of S_SLICES slices of one bucket per block.
// Partials out (coalesced), no global atomics.
__global__ __launch_bounds__(256) void l1r_k(
        const float* __restrict__ x, const float* __restrict__ coeff,
        const int* __restrict__ recs, const int* __restrict__ cnt,
        float* __restrict__ part, int N) {
    __shared__ float p0[R_DSTS], p1[R_DSTS], pc[R_DSTS];
    __shared__ float ac[3 * R_DSTS];
    int t = threadIdx.x;
    int bs = blockIdx.x;
    int b = bs >> 2;
    int sl = bs & 3;
    int nbase = b << R_LOG2;
    int rem = N - nbase; if (rem > R_DSTS) rem = R_DSTS;

    ac[t] = 0.f; ac[256 + t] = 0.f; ac[512 + t] = 0.f;
    if (t < rem) {
        float2 xd = ((const float2*)x)[nbase + t];
        float c0 = coeff[0], c1 = coeff[1], c2 = coeff[2], c3 = coeff[3];
        float c4 = coeff[4], c5 = coeff[5], c6 = coeff[6], c7 = coeff[7];
        float c8 = coeff[8];
        p0[t] = c0 * xd.x + c2 * xd.y + c6;
        p1[t] = c1 * xd.x + c3 * xd.y + c7;
        pc[t] = c4 * xd.x + c5 * xd.y + c8;
    }
    __syncthreads();

    int cb = cnt[b]; if (cb > CAPB) cb = CAPB;
    int len = (cb + S_SLICES - 1) / S_SLICES;
    int lo = sl * len;
    int hi = lo + len; if (hi > cb) hi = cb;
    const int* rb = recs + (size_t)b * CAPB;
    for (int i = lo + t; i < hi; i += 256) {
        int rec = rb[i];
        int s = rec & 0x1FFFF;
        int dl = (rec >> 17) & (R_DSTS - 1);
        float2 xs = ((const float2*)x)[s];
        float w = __expf((p0[dl] * xs.x + p1[dl] * xs.y + pc[dl]) * 0.0625f);
        atomicAdd(&ac[dl], w);
        atomicAdd(&ac[256 + dl], w * xs.x);
        atomicAdd(&ac[512 + dl], w * xs.y);
    }
    __syncthreads();

    float* dp = part + (size_t)bs * (3 * R_DSTS);
    dp[t] = ac[t];
    dp[256 + t] = ac[256 + t];
    dp[512 + t] = ac[512 + t];
}

// Node projection: 8-lane group per FOUR nodes. Weights in LDS; each
// ds_read_b128 is reused for 4 nodes (3.5 LDS instr/node). Slice partials
// reduced via width-4 shuffles; outputs written by lanes 0..3.
__global__ __launch_bounds__(256) void proj_k(
        const float* __restrict__ x, const float* __restrict__ part,
        const float* __restrict__ Wv1, const float* __restrict__ bv1,
        const float* __restrict__ Ws1, const float* __restrict__ bs1,
        const float* __restrict__ Wq2, const float* __restrict__ bq2,
        const float* __restrict__ Wk2, const float* __restrict__ bk2,
        const float* __restrict__ Wv2, const float* __restrict__ bv2,
        const float* __restrict__ Ws2, const float* __restrict__ bs2,
        float* __restrict__ q2, float4* __restrict__ kv2,
        float* __restrict__ hs2, int N) {
    __shared__ float sW[14][256];
    int t = threadIdx.x;
    sW[0][t]  = Wv1[t];
    sW[1][t]  = Wv1[256 + t];
    sW[2][t]  = Ws1[t];
    sW[3][t]  = Ws1[256 + t];
    sW[4][t]  = bv1[t];
    sW[5][t]  = bs1[t];
    sW[6][t]  = Wq2[2 * t];
    sW[7][t]  = Wq2[2 * t + 1];
    sW[8][t]  = Wk2[2 * t];
    sW[9][t]  = Wk2[2 * t + 1];
    sW[10][t] = Wv2[2 * t];
    sW[11][t] = Wv2[2 * t + 1];
    sW[12][t] = Ws2[2 * t];
    sW[13][t] = Ws2[2 * t + 1];
    __syncthreads();

    int g = t & 7;
    int grp = t >> 3;                        // 0..31
    int nb = blockIdx.x * 128 + grp * 4;     // this group's 4 nodes

    // per-node attention params (slice g&3 partial, width-4 xor reduce)
    float a0[4], a1[4], he[4], xdx[4], xdy[4];
#pragma unroll
    for (int k = 0; k < 4; ++k) {
        int n = nb + k;
        float s = 0.f, sx0 = 0.f, sx1 = 0.f;
        if (n < N) {
            int b = n >> R_LOG2, idx = n & (R_DSTS - 1);
            const float* pp = part + ((size_t)(b * S_SLICES + (g & 3))) * (3 * R_DSTS) + idx;
            s = pp[0]; sx0 = pp[256]; sx1 = pp[512];
        }
#pragma unroll
        for (int m = 1; m < 4; m <<= 1) {
            s   += __shfl_xor(s, m);
            sx0 += __shfl_xor(sx0, m);
            sx1 += __shfl_xor(sx1, m);
        }
        a0[k] = 0.f; a1[k] = 0.f; he[k] = 0.f;
        if (s > 0.f) {
            float inv = 1.0f / s;
            a0[k] = sx0 * inv; a1[k] = sx1 * inv; he[k] = 1.f;
        }
        float2 xd = make_float2(0.f, 0.f);
        if (n < N) xd = ((const float2*)x)[n];
        xdx[k] = xd.x; xdy[k] = xd.y;
    }

    float acc[4][8];
#pragma unroll
    for (int k = 0; k < 4; ++k)
#pragma unroll
        for (int i = 0; i < 8; ++i) acc[k][i] = 0.f;

#pragma unroll
    for (int j = 0; j < 8; ++j) {
        int ci = g + 8 * j;  // float4 index; channels 4*ci..4*ci+3
        float4 w0 = ((const float4*)sW[0])[ci];
        float4 w1 = ((const float4*)sW[1])[ci];
        float4 w2 = ((const float4*)sW[2])[ci];
        float4 w3 = ((const float4*)sW[3])[ci];
        float4 w4 = ((const float4*)sW[4])[ci];
        float4 w5 = ((const float4*)sW[5])[ci];
        float4 u0 = ((const float4*)sW[6])[ci];
        float4 u1 = ((const float4*)sW[7])[ci];
        float4 u2 = ((const float4*)sW[8])[ci];
        float4 u3 = ((const float4*)sW[9])[ci];
        float4 u4 = ((const float4*)sW[10])[ci];
        float4 u5 = ((const float4*)sW[11])[ci];
        float4 u6 = ((const float4*)sW[12])[ci];
        float4 u7 = ((const float4*)sW[13])[ci];
#pragma unroll
        for (int k = 0; k < 4; ++k) {
            float4 h;
            h.x = fmaxf(a0[k]*w0.x + a1[k]*w1.x + xdx[k]*w2.x + xdy[k]*w3.x + he[k]*w4.x + w5.x, 0.f);
            h.y = fmaxf(a0[k]*w0.y + a1[k]*w1.y + xdx[k]*w2.y + xdy[k]*w3.y + he[k]*w4.y + w5.y, 0.f);
            h.z = fmaxf(a0[k]*w0.z + a1[k]*w1.z + xdx[k]*w2.z + xdy[k]*w3.z + he[k]*w4.z + w5.z, 0.f);
            h.w = fmaxf(a0[k]*w0.w + a1[k]*w1.w + xdx[k]*w2.w + xdy[k]*w3.w + he[k]*w4.w + w5.w, 0.f);
            acc[k][0] += h.x*u0.x + h.y*u0.y + h.z*u0.z + h.w*u0.w;
            acc[k][1] += h.x*u1.x + h.y*u1.y + h.z*u1.z + h.w*u1.w;
            acc[k][2] += h.x*u2.x + h.y*u2.y + h.z*u2.z + h.w*u2.w;
            acc[k][3] += h.x*u3.x + h.y*u3.y + h.z*u3.z + h.w*u3.w;
            acc[k][4] += h.x*u4.x + h.y*u4.y + h.z*u4.z + h.w*u4.w;
            acc[k][5] += h.x*u5.x + h.y*u5.y + h.z*u5.z + h.w*u5.w;
            acc[k][6] += h.x*u6.x + h.y*u6.y + h.z*u6.z + h.w*u6.w;
            acc[k][7] += h.x*u7.x + h.y*u7.y + h.z*u7.z + h.w*u7.w;
        }
    }
    // width-8 reduce (all lanes end with totals)
#pragma unroll
    for (int k = 0; k < 4; ++k)
#pragma unroll
        for (int i = 0; i < 8; ++i) {
#pragma unroll
            for (int m = 1; m < 8; m <<= 1)
                acc[k][i] += __shfl_xor(acc[k][i], m);
        }
    // lane g (=k) writes node nb+g's outputs
    if (g < 4) {
        int n = nb + g;
        if (n < N) {
            ((float2*)q2)[n]  = make_float2(acc[g][0] + bq2[0], acc[g][1] + bq2[1]);
            kv2[n] = make_float4(acc[g][2] + bk2[0], acc[g][3] + bk2[1],
                                 acc[g][4] + bv2[0], acc[g][5] + bv2[1]);
            ((float2*)hs2)[n] = make_float2(acc[g][6] + bs2[0], acc[g][7] + bs2[1]);
        }
    }
}

// Layer-2 edge reduce (sliced), partials out.
__global__ __launch_bounds__(256) void l2r_k(
        const float* __restrict__ q2, const float4* __restrict__ kv2,
        const int* __restrict__ recs, const int* __restrict__ cnt,
        float* __restrict__ part, int N) {
    __shared__ float qx[R_DSTS], qy[R_DSTS];
    __shared__ float ac[3 * R_DSTS];
    int t = threadIdx.x;
    int bs = blockIdx.x;
    int b = bs >> 2;
    int sl = bs & 3;
    int nbase = b << R_LOG2;
    int rem = N - nbase; if (rem > R_DSTS) rem = R_DSTS;

    ac[t] = 0.f; ac[256 + t] = 0.f; ac[512 + t] = 0.f;
    if (t < rem) {
        float2 q = ((const float2*)q2)[nbase + t];
        qx[t] = q.x * RSQRT2;
        qy[t] = q.y * RSQRT2;
    }
    __syncthreads();

    int cb = cnt[b]; if (cb > CAPB) cb = CAPB;
    int len = (cb + S_SLICES - 1) / S_SLICES;
    int lo = sl * len;
    int hi = lo + len; if (hi > cb) hi = cb;
    const int* rb = recs + (size_t)b * CAPB;
    for (int i = lo + t; i < hi; i += 256) {
        int rec = rb[i];
        int s = rec & 0x1FFFF;
        int dl = (rec >> 17) & (R_DSTS - 1);
        float4 kv = kv2[s];
        float w = __expf(qx[dl] * kv.x + qy[dl] * kv.y);
        atomicAdd(&ac[dl], w);
        atomicAdd(&ac[256 + dl], w * kv.z);
        atomicAdd(&ac[512 + dl], w * kv.w);
    }
    __syncthreads();

    float* dp = part + (size_t)bs * (3 * R_DSTS);
    dp[t] = ac[t];
    dp[256 + t] = ac[256 + t];
    dp[512 + t] = ac[512 + t];
}

// Output: 8-lane group per node reduces layer-2 slice partials (width-4),
// then skip + closed-form 2-class log_softmax.
__global__ __launch_bounds__(256) void out2x_k(
        const float* __restrict__ part, const float* __restrict__ hs2,
        float* __restrict__ out, int N) {
    int t = threadIdx.x;
    int g = t & 7;
    int n = blockIdx.x * 32 + (t >> 3);
    if (n >= N) return;
    int b = n >> R_LOG2, idx = n & (R_DSTS - 1);

    const float* pp = part + ((size_t)(b * S_SLICES + (g & 3))) * (3 * R_DSTS) + idx;
    float s = pp[0], sv0 = pp[256], sv1 = pp[512];
#pragma unroll
    for (int m = 1; m < 4; m <<= 1) {
        s   += __shfl_xor(s, m);
        sv0 += __shfl_xor(sv0, m);
        sv1 += __shfl_xor(sv1, m);
    }
    if (g != 0) return;

    float g0 = 0.f, g1 = 0.f;
    if (s > 0.f) {
        float inv = 1.0f / s;
        g0 = sv0 * inv; g1 = sv1 * inv;
    }
    float2 hs = ((const float2*)hs2)[n];
    float o0 = g0 + hs.x;
    float o1 = g1 + hs.y;
    float mx = fmaxf(o0, o1), mn = fminf(o0, o1);
    float lse = mx + log1pf(__expf(mn - mx));
    ((float2*)out)[n] = make_float2(o0 - lse, o1 - lse);
}

extern "C" void kernel_launch(void* const* d_in, const int* in_sizes, int n_in,
                              void* d_out, int out_size, void* d_ws, size_t ws_size,
                              hipStream_t stream) {
    const float* x   = (const float*)d_in[0];
    const int*   ei  = (const int*)d_in[1];
    const float* Wq1 = (const float*)d_in[2];
    const float* bq1 = (const float*)d_in[3];
    const float* Wk1 = (const float*)d_in[4];
    const float* bk1 = (const float*)d_in[5];
    const float* Wv1 = (const float*)d_in[6];
    const float* bv1 = (const float*)d_in[7];
    const float* Ws1 = (const float*)d_in[8];
    const float* bs1 = (const float*)d_in[9];
    const float* Wq2 = (const float*)d_in[10];
    const float* bq2 = (const float*)d_in[11];
    const float* Wk2 = (const float*)d_in[12];
    const float* bk2 = (const float*)d_in[13];
    const float* Wv2 = (const float*)d_in[14];
    const float* bv2 = (const float*)d_in[15];
    const float* Ws2 = (const float*)d_in[16];
    const float* bs2 = (const float*)d_in[17];

    const int N = in_sizes[0] / 2;
    const int E = in_sizes[1] / 2;
    const int* src = ei;
    const int* dst = ei + E;

    const int NB   = (N + R_DSTS - 1) >> R_LOG2;     // 391
    const int NBlk = (E + BE - 1) / BE;              // 391

    // workspace layout (4-byte units)
    float* ws = (float*)d_ws;
    size_t off = 0;
    float* coeff = ws + off;                 off += 16;
    int*   cnt   = (int*)(ws + off);         off += NB;
    int*   recs  = (int*)(ws + off);         off += (size_t)NB * CAPB;
    off = (off + 3) & ~(size_t)3;            // 16B align
    float* part  = ws + off;                 off += (size_t)NB * S_SLICES * 3 * R_DSTS;
    float4* kv2  = (float4*)(ws + off);      off += 4 * (size_t)N;
    float* q2    = ws + off;                 off += 2 * (size_t)N;
    float* hs2   = ws + off;                 off += 2 * (size_t)N;

    const int gP  = (N + 127) / 128;   // proj: 128 nodes/block
    const int gO  = (N + 31) / 32;     // out2x: 32 nodes/block

    hipMemsetAsync(cnt, 0, NB * sizeof(int), stream);
    coeff_k<<<1, 256, 0, stream>>>(Wq1, bq1, Wk1, bk1, coeff);
    scatter1_k<<<NBlk, 256, 0, stream>>>(src, dst, cnt, recs, NB, E);
    l1r_k<<<NB * S_SLICES, 256, 0, stream>>>(x, coeff, recs, cnt, part, N);
    proj_k<<<gP, 256, 0, stream>>>(x, part, Wv1, bv1, Ws1, bs1,
                                   Wq2, bq2, Wk2, bk2, Wv2, bv2, Ws2, bs2,
                                   q2, kv2, hs2, N);
    l2r_k<<<NB * S_SLICES, 256, 0, stream>>>(q2, kv2, recs, cnt, part, N);
    out2x_k<<<gO, 256, 0, stream>>>(part, hs2, (float*)d_out, N);
}

// Round 13
// 127.846 us; speedup vs baseline: 1.1267x; 1.1267x over previous
//
#include <hip/hip_runtime.h>

// ---------------------------------------------------------------------------
// 2-layer TransformerConv factored through the 2-dim feature spaces.
// Round 13: round 12's proj_k regressed (VGPR 204 -> 7.9% occupancy) because
// the fully-unrolled j-loop kept 14 float4 weights x N iterations live.
// Keep the 4-nodes-per-group LDS amortization (correct for the LDS pipe:
// ~7us floor) but: #pragma unroll 1 on the j-loop, two-phase body (w's ->
// h[4] -> u's one at a time), __launch_bounds__(256,3). Rest unchanged.
// ---------------------------------------------------------------------------

#define R_LOG2   8
#define R_DSTS   256            // dsts per bucket
#define BE       4096           // edges per partition block
#define MAXNB    512            // supports N <= 131072
#define CAPB     4608           // slots per bucket (mean 4096, sd 64 -> 8 sigma)
#define S_SLICES 4              // edge slices per bucket
#define RSQRT2   0.70710678118654752f

// 9 reduction coefficients for the layer-1 bilinear attention form:
// q1(d).k1(s) = xd^T M xs + u.xd + w.xs + c   (before 1/16 scale)
__global__ void coeff_k(const float* __restrict__ Wq1, const float* __restrict__ bq1,
                        const float* __restrict__ Wk1, const float* __restrict__ bk1,
                        float* __restrict__ coeff) {
    __shared__ float part[4][9];
    int c = threadIdx.x;  // 256 threads
    float wq0 = Wq1[c], wq1 = Wq1[256 + c];
    float wk0 = Wk1[c], wk1 = Wk1[256 + c];
    float bq = bq1[c], bk = bk1[c];
    float vals[9] = { wq0 * wk0, wq0 * wk1, wq1 * wk0, wq1 * wk1,
                      wq0 * bk,  wq1 * bk,  bq * wk0,  bq * wk1,  bq * bk };
    int lane = c & 63, w = c >> 6;
#pragma unroll
    for (int i = 0; i < 9; ++i) {
        float v = vals[i];
#pragma unroll
        for (int o = 32; o > 0; o >>= 1) v += __shfl_xor(v, o);
        if (lane == 0) part[w][i] = v;
    }
    __syncthreads();
    if (c < 9) coeff[c] = part[0][c] + part[1][c] + part[2][c] + part[3][c];
}

// Single-pass locally-sorted scatter: LDS histogram -> in-block scan ->
// global segment reservation (1 atomicAdd per touched bucket) -> rank &
// stage in bucket order -> ordered coalesced segment writes.
__global__ __launch_bounds__(256) void scatter1_k(
        const int* __restrict__ src, const int* __restrict__ dst,
        int* __restrict__ cnt, int* __restrict__ recs, int NB, int E) {
    __shared__ int hist[MAXNB];
    __shared__ int lofs[MAXNB];
    __shared__ int gbase[MAXNB];
    __shared__ int stage[BE];
    __shared__ unsigned short sbkt[BE];
    __shared__ int wsum[4];
    int t = threadIdx.x;
    for (int i = t; i < NB; i += 256) hist[i] = 0;
    __syncthreads();

    int base = blockIdx.x * BE;
    int nloc = E - base; if (nloc > BE) nloc = BE;
    int nv = nloc >> 2;
    const int4* d4 = (const int4*)(dst + base);
    const int4* s4 = (const int4*)(src + base);

    // pass 1: local histogram
    for (int i = t; i < nv; i += 256) {
        int4 v = d4[i];
        atomicAdd(&hist[v.x >> R_LOG2], 1);
        atomicAdd(&hist[v.y >> R_LOG2], 1);
        atomicAdd(&hist[v.z >> R_LOG2], 1);
        atomicAdd(&hist[v.w >> R_LOG2], 1);
    }
    for (int i = (nv << 2) + t; i < nloc; i += 256)
        atomicAdd(&hist[dst[base + i] >> R_LOG2], 1);
    __syncthreads();

    // in-block exclusive scan hist -> lofs (2 entries per thread, NB<=512)
    {
        int i0 = 2 * t, i1 = 2 * t + 1;
        int a = (i0 < NB) ? hist[i0] : 0;
        int b = (i1 < NB) ? hist[i1] : 0;
        int s = a + b;
        int lane = t & 63, w = t >> 6;
        int incl = s;
#pragma unroll
        for (int o = 1; o < 64; o <<= 1) {
            int u = __shfl_up(incl, o);
            if (lane >= o) incl += u;
        }
        if (lane == 63) wsum[w] = incl;
        __syncthreads();
        int ex = incl - s;
        for (int j = 0; j < w; ++j) ex += wsum[j];
        if (i0 < NB) lofs[i0] = ex;
        if (i1 < NB) lofs[i1] = ex + a;
    }
    __syncthreads();

    // reserve a contiguous segment in each touched bucket, reset hist
    for (int b = t; b < NB; b += 256) {
        int h = hist[b];
        int start = h ? atomicAdd(&cnt[b], h) : 0;
        gbase[b] = b * CAPB + start - lofs[b];
        hist[b] = 0;
    }
    __syncthreads();

    // pass 2: rank & stage in bucket-sorted order
    for (int i = t; i < nv; i += 256) {
        int4 dv = d4[i];
        int4 sv = s4[i];
        int d, b, r, p;
        d = dv.x; b = d >> R_LOG2; r = atomicAdd(&hist[b], 1); p = lofs[b] + r;
        stage[p] = sv.x | ((d & (R_DSTS - 1)) << 17); sbkt[p] = (unsigned short)b;
        d = dv.y; b = d >> R_LOG2; r = atomicAdd(&hist[b], 1); p = lofs[b] + r;
        stage[p] = sv.y | ((d & (R_DSTS - 1)) << 17); sbkt[p] = (unsigned short)b;
        d = dv.z; b = d >> R_LOG2; r = atomicAdd(&hist[b], 1); p = lofs[b] + r;
        stage[p] = sv.z | ((d & (R_DSTS - 1)) << 17); sbkt[p] = (unsigned short)b;
        d = dv.w; b = d >> R_LOG2; r = atomicAdd(&hist[b], 1); p = lofs[b] + r;
        stage[p] = sv.w | ((d & (R_DSTS - 1)) << 17); sbkt[p] = (unsigned short)b;
    }
    for (int i = (nv << 2) + t; i < nloc; i += 256) {
        int d = dst[base + i];
        int b = d >> R_LOG2;
        int r = atomicAdd(&hist[b], 1);
        int p = lofs[b] + r;
        stage[p] = src[base + i] | ((d & (R_DSTS - 1)) << 17);
        sbkt[p] = (unsigned short)b;
    }
    __syncthreads();

    // pass 3: ordered write — consecutive i -> consecutive addresses per
    // segment; bound-checked against the bucket's fixed capacity.
    for (int i = t; i < nloc; i += 256) {
        int bk = sbkt[i];
        int p = gbase[bk] + i;
        if (p < (bk + 1) * CAPB) recs[p] = stage[i];
    }
}

// Layer-1 edge reduce, one of S_SLICES slices of one bucket per block.
// Partials out (coalesced), no global atomics.
__global__ __launch_bounds__(256) void l1r_k(
        const float* __restrict__ x, const float* __restrict__ coeff,
        const int* __restrict__ recs, const int* __restrict__ cnt,
        float* __restrict__ part, int N) {
    __shared__ float p0[R_DSTS], p1[R_DSTS], pc[R_DSTS];
    __shared__ float ac[3 * R_DSTS];
    int t = threadIdx.x;
    int bs = blockIdx.x;
    int b = bs >> 2;
    int sl = bs & 3;
    int nbase = b << R_LOG2;
    int rem = N - nbase; if (rem > R_DSTS) rem = R_DSTS;

    ac[t] = 0.f; ac[256 + t] = 0.f; ac[512 + t] = 0.f;
    if (t < rem) {
        float2 xd = ((const float2*)x)[nbase + t];
        float c0 = coeff[0], c1 = coeff[1], c2 = coeff[2], c3 = coeff[3];
        float c4 = coeff[4], c5 = coeff[5], c6 = coeff[6], c7 = coeff[7];
        float c8 = coeff[8];
        p0[t] = c0 * xd.x + c2 * xd.y + c6;
        p1[t] = c1 * xd.x + c3 * xd.y + c7;
        pc[t] = c4 * xd.x + c5 * xd.y + c8;
    }
    __syncthreads();

    int cb = cnt[b]; if (cb > CAPB) cb = CAPB;
    int len = (cb + S_SLICES - 1) / S_SLICES;
    int lo = sl * len;
    int hi = lo + len; if (hi > cb) hi = cb;
    const int* rb = recs + (size_t)b * CAPB;
    for (int i = lo + t; i < hi; i += 256) {
        int rec = rb[i];
        int s = rec & 0x1FFFF;
        int dl = (rec >> 17) & (R_DSTS - 1);
        float2 xs = ((const float2*)x)[s];
        float w = __expf((p0[dl] * xs.x + p1[dl] * xs.y + pc[dl]) * 0.0625f);
        atomicAdd(&ac[dl], w);
        atomicAdd(&ac[256 + dl], w * xs.x);
        atomicAdd(&ac[512 + dl], w * xs.y);
    }
    __syncthreads();

    float* dp = part + (size_t)bs * (3 * R_DSTS);
    dp[t] = ac[t];
    dp[256 + t] = ac[256 + t];
    dp[512 + t] = ac[512 + t];
}

// Node projection: 8-lane group per FOUR nodes; weight reads amortized 4x.
// j-loop NOT unrolled and body phased (w's -> h -> u's one at a time) to
// keep peak live registers ~100.
__global__ __launch_bounds__(256, 3) void proj_k(
        const float* __restrict__ x, const float* __restrict__ part,
        const float* __restrict__ Wv1, const float* __restrict__ bv1,
        const float* __restrict__ Ws1, const float* __restrict__ bs1,
        const float* __restrict__ Wq2, const float* __restrict__ bq2,
        const float* __restrict__ Wk2, const float* __restrict__ bk2,
        const float* __restrict__ Wv2, const float* __restrict__ bv2,
        const float* __restrict__ Ws2, const float* __restrict__ bs2,
        float* __restrict__ q2, float4* __restrict__ kv2,
        float* __restrict__ hs2, int N) {
    __shared__ float sW[14][256];
    int t = threadIdx.x;
    sW[0][t]  = Wv1[t];
    sW[1][t]  = Wv1[256 + t];
    sW[2][t]  = Ws1[t];
    sW[3][t]  = Ws1[256 + t];
    sW[4][t]  = bv1[t];
    sW[5][t]  = bs1[t];
    sW[6][t]  = Wq2[2 * t];
    sW[7][t]  = Wq2[2 * t + 1];
    sW[8][t]  = Wk2[2 * t];
    sW[9][t]  = Wk2[2 * t + 1];
    sW[10][t] = Wv2[2 * t];
    sW[11][t] = Wv2[2 * t + 1];
    sW[12][t] = Ws2[2 * t];
    sW[13][t] = Ws2[2 * t + 1];
    __syncthreads();

    int g = t & 7;
    int grp = t >> 3;                        // 0..31
    int nb = blockIdx.x * 128 + grp * 4;     // this group's 4 nodes

    // per-node attention params (slice g&3 partial, width-4 xor reduce)
    float a0[4], a1[4], he[4], xdx[4], xdy[4];
#pragma unroll
    for (int k = 0; k < 4; ++k) {
        int n = nb + k;
        float s = 0.f, sx0 = 0.f, sx1 = 0.f;
        if (n < N) {
            int b = n >> R_LOG2, idx = n & (R_DSTS - 1);
            const float* pp = part + ((size_t)(b * S_SLICES + (g & 3))) * (3 * R_DSTS) + idx;
            s = pp[0]; sx0 = pp[256]; sx1 = pp[512];
        }
#pragma unroll
        for (int m = 1; m < 4; m <<= 1) {
            s   += __shfl_xor(s, m);
            sx0 += __shfl_xor(sx0, m);
            sx1 += __shfl_xor(sx1, m);
        }
        a0[k] = 0.f; a1[k] = 0.f; he[k] = 0.f;
        if (s > 0.f) {
            float inv = 1.0f / s;
            a0[k] = sx0 * inv; a1[k] = sx1 * inv; he[k] = 1.f;
        }
        float2 xd = make_float2(0.f, 0.f);
        if (n < N) xd = ((const float2*)x)[n];
        xdx[k] = xd.x; xdy[k] = xd.y;
    }

    float acc[4][8];
#pragma unroll
    for (int k = 0; k < 4; ++k)
#pragma unroll
        for (int i = 0; i < 8; ++i) acc[k][i] = 0.f;

#pragma unroll 1
    for (int j = 0; j < 8; ++j) {
        int ci = g + 8 * j;  // float4 index; channels 4*ci..4*ci+3
        // phase 1: hidden activations for the 4 nodes (w0..w5 live)
        float4 hk[4];
        {
            float4 w0 = ((const float4*)sW[0])[ci];
            float4 w1 = ((const float4*)sW[1])[ci];
            float4 w2 = ((const float4*)sW[2])[ci];
            float4 w3 = ((const float4*)sW[3])[ci];
            float4 w4 = ((const float4*)sW[4])[ci];
            float4 w5 = ((const float4*)sW[5])[ci];
#pragma unroll
            for (int k = 0; k < 4; ++k) {
                hk[k].x = fmaxf(a0[k]*w0.x + a1[k]*w1.x + xdx[k]*w2.x + xdy[k]*w3.x + he[k]*w4.x + w5.x, 0.f);
                hk[k].y = fmaxf(a0[k]*w0.y + a1[k]*w1.y + xdx[k]*w2.y + xdy[k]*w3.y + he[k]*w4.y + w5.y, 0.f);
                hk[k].z = fmaxf(a0[k]*w0.z + a1[k]*w1.z + xdx[k]*w2.z + xdy[k]*w3.z + he[k]*w4.z + w5.z, 0.f);
                hk[k].w = fmaxf(a0[k]*w0.w + a1[k]*w1.w + xdx[k]*w2.w + xdy[k]*w3.w + he[k]*w4.w + w5.w, 0.f);
            }
        }
        // phase 2: project, one output weight vector at a time
#pragma unroll
        for (int i = 0; i < 8; ++i) {
            float4 u = ((const float4*)sW[6 + i])[ci];
#pragma unroll
            for (int k = 0; k < 4; ++k)
                acc[k][i] += hk[k].x*u.x + hk[k].y*u.y + hk[k].z*u.z + hk[k].w*u.w;
        }
    }
    // width-8 reduce (all lanes end with totals)
#pragma unroll
    for (int k = 0; k < 4; ++k)
#pragma unroll
        for (int i = 0; i < 8; ++i) {
#pragma unroll
            for (int m = 1; m < 8; m <<= 1)
                acc[k][i] += __shfl_xor(acc[k][i], m);
        }
    // lane g (=k) writes node nb+g's outputs
    if (g < 4) {
        int n = nb + g;
        if (n < N) {
            ((float2*)q2)[n]  = make_float2(acc[g][0] + bq2[0], acc[g][1] + bq2[1]);
            kv2[n] = make_float4(acc[g][2] + bk2[0], acc[g][3] + bk2[1],
                                 acc[g][4] + bv2[0], acc[g][5] + bv2[1]);
            ((float2*)hs2)[n] = make_float2(acc[g][6] + bs2[0], acc[g][7] + bs2[1]);
        }
    }
}

// Layer-2 edge reduce (sliced), partials out.
__global__ __launch_bounds__(256) void l2r_k(
        const float* __restrict__ q2, const float4* __restrict__ kv2,
        const int* __restrict__ recs, const int* __restrict__ cnt,
        float* __restrict__ part, int N) {
    __shared__ float qx[R_DSTS], qy[R_DSTS];
    __shared__ float ac[3 * R_DSTS];
    int t = threadIdx.x;
    int bs = blockIdx.x;
    int b = bs >> 2;
    int sl = bs & 3;
    int nbase = b << R_LOG2;
    int rem = N - nbase; if (rem > R_DSTS) rem = R_DSTS;

    ac[t] = 0.f; ac[256 + t] = 0.f; ac[512 + t] = 0.f;
    if (t < rem) {
        float2 q = ((const float2*)q2)[nbase + t];
        qx[t] = q.x * RSQRT2;
        qy[t] = q.y * RSQRT2;
    }
    __syncthreads();

    int cb = cnt[b]; if (cb > CAPB) cb = CAPB;
    int len = (cb + S_SLICES - 1) / S_SLICES;
    int lo = sl * len;
    int hi = lo + len; if (hi > cb) hi = cb;
    const int* rb = recs + (size_t)b * CAPB;
    for (int i = lo + t; i < hi; i += 256) {
        int rec = rb[i];
        int s = rec & 0x1FFFF;
        int dl = (rec >> 17) & (R_DSTS - 1);
        float4 kv = kv2[s];
        float w = __expf(qx[dl] * kv.x + qy[dl] * kv.y);
        atomicAdd(&ac[dl], w);
        atomicAdd(&ac[256 + dl], w * kv.z);
        atomicAdd(&ac[512 + dl], w * kv.w);
    }
    __syncthreads();

    float* dp = part + (size_t)bs * (3 * R_DSTS);
    dp[t] = ac[t];
    dp[256 + t] = ac[256 + t];
    dp[512 + t] = ac[512 + t];
}

// Output: 8-lane group per node reduces layer-2 slice partials (width-4),
// then skip + closed-form 2-class log_softmax.
__global__ __launch_bounds__(256) void out2x_k(
        const float* __restrict__ part, const float* __restrict__ hs2,
        float* __restrict__ out, int N) {
    int t = threadIdx.x;
    int g = t & 7;
    int n = blockIdx.x * 32 + (t >> 3);
    if (n >= N) return;
    int b = n >> R_LOG2, idx = n & (R_DSTS - 1);

    const float* pp = part + ((size_t)(b * S_SLICES + (g & 3))) * (3 * R_DSTS) + idx;
    float s = pp[0], sv0 = pp[256], sv1 = pp[512];
#pragma unroll
    for (int m = 1; m < 4; m <<= 1) {
        s   += __shfl_xor(s, m);
        sv0 += __shfl_xor(sv0, m);
        sv1 += __shfl_xor(sv1, m);
    }
    if (g != 0) return;

    float g0 = 0.f, g1 = 0.f;
    if (s > 0.f) {
        float inv = 1.0f / s;
        g0 = sv0 * inv; g1 = sv1 * inv;
    }
    float2 hs = ((const float2*)hs2)[n];
    float o0 = g0 + hs.x;
    float o1 = g1 + hs.y;
    float mx = fmaxf(o0, o1), mn = fminf(o0, o1);
    float lse = mx + log1pf(__expf(mn - mx));
    ((float2*)out)[n] = make_float2(o0 - lse, o1 - lse);
}

extern "C" void kernel_launch(void* const* d_in, const int* in_sizes, int n_in,
                              void* d_out, int out_size, void* d_ws, size_t ws_size,
                              hipStream_t stream) {
    const float* x   = (const float*)d_in[0];
    const int*   ei  = (const int*)d_in[1];
    const float* Wq1 = (const float*)d_in[2];
    const float* bq1 = (const float*)d_in[3];
    const float* Wk1 = (const float*)d_in[4];
    const float* bk1 = (const float*)d_in[5];
    const float* Wv1 = (const float*)d_in[6];
    const float* bv1 = (const float*)d_in[7];
    const float* Ws1 = (const float*)d_in[8];
    const float* bs1 = (const float*)d_in[9];
    const float* Wq2 = (const float*)d_in[10];
    const float* bq2 = (const float*)d_in[11];
    const float* Wk2 = (const float*)d_in[12];
    const float* bk2 = (const float*)d_in[13];
    const float* Wv2 = (const float*)d_in[14];
    const float* bv2 = (const float*)d_in[15];
    const float* Ws2 = (const float*)d_in[16];
    const float* bs2 = (const float*)d_in[17];

    const int N = in_sizes[0] / 2;
    const int E = in_sizes[1] / 2;
    const int* src = ei;
    const int* dst = ei + E;

    const int NB   = (N + R_DSTS - 1) >> R_LOG2;     // 391
    const int NBlk = (E + BE - 1) / BE;              // 391

    // workspace layout (4-byte units)
    float* ws = (float*)d_ws;
    size_t off = 0;
    float* coeff = ws + off;                 off += 16;
    int*   cnt   = (int*)(ws + off);         off += NB;
    int*   recs  = (int*)(ws + off);         off += (size_t)NB * CAPB;
    off = (off + 3) & ~(size_t)3;            // 16B align
    float* part  = ws + off;                 off += (size_t)NB * S_SLICES * 3 * R_DSTS;
    float4* kv2  = (float4*)(ws + off);      off += 4 * (size_t)N;
    float* q2    = ws + off;                 off += 2 * (size_t)N;
    float* hs2   = ws + off;                 off += 2 * (size_t)N;

    const int gP  = (N + 127) / 128;   // proj: 128 nodes/block
    const int gO  = (N + 31) / 32;     // out2x: 32 nodes/block

    hipMemsetAsync(cnt, 0, NB * sizeof(int), stream);
    coeff_k<<<1, 256, 0, stream>>>(Wq1, bq1, Wk1, bk1, coeff);
    scatter1_k<<<NBlk, 256, 0, stream>>>(src, dst, cnt, recs, NB, E);
    l1r_k<<<NB * S_SLICES, 256, 0, stream>>>(x, coeff, recs, cnt, part, N);
    proj_k<<<gP, 256, 0, stream>>>(x, part, Wv1, bv1, Ws1, bs1,
                                   Wq2, bq2, Wk2, bk2, Wv2, bv2, Ws2, bs2,
                                   q2, kv2, hs2, N);
    l2r_k<<<NB * S_SLICES, 256, 0, stream>>>(q2, kv2, recs, cnt, part, N);
    out2x_k<<<gO, 256, 0, stream>>>(part, hs2, (float*)d_out, N);
}

// Round 14
// 123.013 us; speedup vs baseline: 1.1710x; 1.0393x over previous
//
#include <hip/hip_runtime.h>

// ---------------------------------------------------------------------------
// 2-layer TransformerConv factored through the 2-dim feature spaces.
// Round 14: occupancy pass. Every measured-slow kernel had grid ~391 blocks
// (1.5 blocks/CU, latencies exposed). scatter -> 1024-thread blocks (16
// waves/block); proj -> 2-node groups (1563 blocks); coeff folded into l1r.
// 6 dispatches.
// ---------------------------------------------------------------------------

#define R_LOG2   8
#define R_DSTS   256            // dsts per bucket
#define BE       4096           // edges per partition block
#define MAXNB    512            // supports N <= 131072
#define CAPB     4608           // slots per bucket (mean 4096, sd 64 -> 8 sigma)
#define S_SLICES 4              // edge slices per bucket
#define RSQRT2   0.70710678118654752f

// Single-pass locally-sorted scatter, 1024 threads (16 waves) per block for
// latency hiding. LDS histogram -> in-block scan -> global segment
// reservation (1 atomicAdd per touched bucket) -> rank & stage in bucket
// order -> ordered coalesced segment writes.
__global__ __launch_bounds__(1024) void scatter1_k(
        const int* __restrict__ src, const int* __restrict__ dst,
        int* __restrict__ cnt, int* __restrict__ recs, int NB, int E) {
    __shared__ int hist[MAXNB];
    __shared__ int lofs[MAXNB];
    __shared__ int gbase[MAXNB];
    __shared__ int stage[BE];
    __shared__ unsigned short sbkt[BE];
    __shared__ int wsum[16];
    int t = threadIdx.x;
    if (t < NB) hist[t] = 0;
    __syncthreads();

    int base = blockIdx.x * BE;
    int nloc = E - base; if (nloc > BE) nloc = BE;
    int nv = nloc >> 2;
    const int4* d4 = (const int4*)(dst + base);
    const int4* s4 = (const int4*)(src + base);

    // pass 1: local histogram (4 edges/thread via int4)
    for (int i = t; i < nv; i += 1024) {
        int4 v = d4[i];
        atomicAdd(&hist[v.x >> R_LOG2], 1);
        atomicAdd(&hist[v.y >> R_LOG2], 1);
        atomicAdd(&hist[v.z >> R_LOG2], 1);
        atomicAdd(&hist[v.w >> R_LOG2], 1);
    }
    for (int i = (nv << 2) + t; i < nloc; i += 1024)
        atomicAdd(&hist[dst[base + i] >> R_LOG2], 1);
    __syncthreads();

    // in-block exclusive scan hist -> lofs (1 entry/thread, NB<=512<=1024)
    {
        int v = (t < NB) ? hist[t] : 0;
        int lane = t & 63, w = t >> 6;   // 16 waves
        int incl = v;
#pragma unroll
        for (int o = 1; o < 64; o <<= 1) {
            int u = __shfl_up(incl, o);
            if (lane >= o) incl += u;
        }
        if (lane == 63) wsum[w] = incl;
        __syncthreads();
        int ex = incl - v;
        for (int j = 0; j < w; ++j) ex += wsum[j];
        if (t < NB) lofs[t] = ex;
    }
    __syncthreads();

    // reserve a contiguous segment in each touched bucket, reset hist
    if (t < NB) {
        int h = hist[t];
        int start = h ? atomicAdd(&cnt[t], h) : 0;
        gbase[t] = t * CAPB + start - lofs[t];
        hist[t] = 0;
    }
    __syncthreads();

    // pass 2: rank & stage in bucket-sorted order
    for (int i = t; i < nv; i += 1024) {
        int4 dv = d4[i];
        int4 sv = s4[i];
        int d, b, r, p;
        d = dv.x; b = d >> R_LOG2; r = atomicAdd(&hist[b], 1); p = lofs[b] + r;
        stage[p] = sv.x | ((d & (R_DSTS - 1)) << 17); sbkt[p] = (unsigned short)b;
        d = dv.y; b = d >> R_LOG2; r = atomicAdd(&hist[b], 1); p = lofs[b] + r;
        stage[p] = sv.y | ((d & (R_DSTS - 1)) << 17); sbkt[p] = (unsigned short)b;
        d = dv.z; b = d >> R_LOG2; r = atomicAdd(&hist[b], 1); p = lofs[b] + r;
        stage[p] = sv.z | ((d & (R_DSTS - 1)) << 17); sbkt[p] = (unsigned short)b;
        d = dv.w; b = d >> R_LOG2; r = atomicAdd(&hist[b], 1); p = lofs[b] + r;
        stage[p] = sv.w | ((d & (R_DSTS - 1)) << 17); sbkt[p] = (unsigned short)b;
    }
    for (int i = (nv << 2) + t; i < nloc; i += 1024) {
        int d = dst[base + i];
        int b = d >> R_LOG2;
        int r = atomicAdd(&hist[b], 1);
        int p = lofs[b] + r;
        stage[p] = src[base + i] | ((d & (R_DSTS - 1)) << 17);
        sbkt[p] = (unsigned short)b;
    }
    __syncthreads();

    // pass 3: ordered write — consecutive i -> consecutive addresses per
    // segment; bound-checked against the bucket's fixed capacity.
    for (int i = t; i < nloc; i += 1024) {
        int bk = sbkt[i];
        int p = gbase[bk] + i;
        if (p < (bk + 1) * CAPB) recs[p] = stage[i];
    }
}

// Layer-1 edge reduce, one of S_SLICES slices of one bucket per block.
// The 9 bilinear coefficients (alpha = xd^T M xs + u.xd + w.xs + c) are
// computed locally per block (6 L2-hot loads + butterflies) -- no separate
// coeff kernel. Partials out (coalesced), no global atomics.
__global__ __launch_bounds__(256) void l1r_k(
        const float* __restrict__ x,
        const float* __restrict__ Wq1, const float* __restrict__ bq1,
        const float* __restrict__ Wk1, const float* __restrict__ bk1,
        const int* __restrict__ recs, const int* __restrict__ cnt,
        float* __restrict__ part, int N) {
    __shared__ float p0[R_DSTS], p1[R_DSTS], pc[R_DSTS];
    __shared__ float ac[3 * R_DSTS];
    __shared__ float cpart[4][9];
    __shared__ float c9[9];
    int t = threadIdx.x;

    // inline coeff reduction
    {
        float wq0 = Wq1[t], wq1 = Wq1[256 + t];
        float wk0 = Wk1[t], wk1 = Wk1[256 + t];
        float bq = bq1[t], bk = bk1[t];
        float vals[9] = { wq0 * wk0, wq0 * wk1, wq1 * wk0, wq1 * wk1,
                          wq0 * bk,  wq1 * bk,  bq * wk0,  bq * wk1,  bq * bk };
        int lane = t & 63, w = t >> 6;
#pragma unroll
        for (int i = 0; i < 9; ++i) {
            float v = vals[i];
#pragma unroll
            for (int o = 32; o > 0; o >>= 1) v += __shfl_xor(v, o);
            if (lane == 0) cpart[w][i] = v;
        }
        __syncthreads();
        if (t < 9) c9[t] = cpart[0][t] + cpart[1][t] + cpart[2][t] + cpart[3][t];
        __syncthreads();
    }

    int bs = blockIdx.x;
    int b = bs >> 2;
    int sl = bs & 3;
    int nbase = b << R_LOG2;
    int rem = N - nbase; if (rem > R_DSTS) rem = R_DSTS;

    ac[t] = 0.f; ac[256 + t] = 0.f; ac[512 + t] = 0.f;
    if (t < rem) {
        float2 xd = ((const float2*)x)[nbase + t];
        p0[t] = c9[0] * xd.x + c9[2] * xd.y + c9[6];
        p1[t] = c9[1] * xd.x + c9[3] * xd.y + c9[7];
        pc[t] = c9[4] * xd.x + c9[5] * xd.y + c9[8];
    }
    __syncthreads();

    int cb = cnt[b]; if (cb > CAPB) cb = CAPB;
    int len = (cb + S_SLICES - 1) / S_SLICES;
    int lo = sl * len;
    int hi = lo + len; if (hi > cb) hi = cb;
    const int* rb = recs + (size_t)b * CAPB;
    for (int i = lo + t; i < hi; i += 256) {
        int rec = rb[i];
        int s = rec & 0x1FFFF;
        int dl = (rec >> 17) & (R_DSTS - 1);
        float2 xs = ((const float2*)x)[s];
        float w = __expf((p0[dl] * xs.x + p1[dl] * xs.y + pc[dl]) * 0.0625f);
        atomicAdd(&ac[dl], w);
        atomicAdd(&ac[256 + dl], w * xs.x);
        atomicAdd(&ac[512 + dl], w * xs.y);
    }
    __syncthreads();

    float* dp = part + (size_t)bs * (3 * R_DSTS);
    dp[t] = ac[t];
    dp[256 + t] = ac[256 + t];
    dp[512 + t] = ac[512 + t];
}

// Node projection: 8-lane group per TWO nodes (64 nodes/block, 1563 blocks
// -> ~4 resident blocks/CU). Weights in LDS, each read reused 2x; phased
// low-register body (#pragma unroll 1, w's -> h -> u's one at a time).
__global__ __launch_bounds__(256, 4) void proj_k(
        const float* __restrict__ x, const float* __restrict__ part,
        const float* __restrict__ Wv1, const float* __restrict__ bv1,
        const float* __restrict__ Ws1, const float* __restrict__ bs1,
        const float* __restrict__ Wq2, const float* __restrict__ bq2,
        const float* __restrict__ Wk2, const float* __restrict__ bk2,
        const float* __restrict__ Wv2, const float* __restrict__ bv2,
        const float* __restrict__ Ws2, const float* __restrict__ bs2,
        float* __restrict__ q2, float4* __restrict__ kv2,
        float* __restrict__ hs2, int N) {
    __shared__ float sW[14][256];
    int t = threadIdx.x;
    sW[0][t]  = Wv1[t];
    sW[1][t]  = Wv1[256 + t];
    sW[2][t]  = Ws1[t];
    sW[3][t]  = Ws1[256 + t];
    sW[4][t]  = bv1[t];
    sW[5][t]  = bs1[t];
    sW[6][t]  = Wq2[2 * t];
    sW[7][t]  = Wq2[2 * t + 1];
    sW[8][t]  = Wk2[2 * t];
    sW[9][t]  = Wk2[2 * t + 1];
    sW[10][t] = Wv2[2 * t];
    sW[11][t] = Wv2[2 * t + 1];
    sW[12][t] = Ws2[2 * t];
    sW[13][t] = Ws2[2 * t + 1];
    __syncthreads();

    int g = t & 7;
    int grp = t >> 3;                       // 0..31
    int nb = blockIdx.x * 64 + grp * 2;     // this group's 2 nodes

    // per-node attention params (slice g&3 partial, width-4 xor reduce)
    float a0[2], a1[2], he[2], xdx[2], xdy[2];
#pragma unroll
    for (int k = 0; k < 2; ++k) {
        int n = nb + k;
        float s = 0.f, sx0 = 0.f, sx1 = 0.f;
        if (n < N) {
            int b = n >> R_LOG2, idx = n & (R_DSTS - 1);
            const float* pp = part + ((size_t)(b * S_SLICES + (g & 3))) * (3 * R_DSTS) + idx;
            s = pp[0]; sx0 = pp[256]; sx1 = pp[512];
        }
#pragma unroll
        for (int m = 1; m < 4; m <<= 1) {
            s   += __shfl_xor(s, m);
            sx0 += __shfl_xor(sx0, m);
            sx1 += __shfl_xor(sx1, m);
        }
        a0[k] = 0.f; a1[k] = 0.f; he[k] = 0.f;
        if (s > 0.f) {
            float inv = 1.0f / s;
            a0[k] = sx0 * inv; a1[k] = sx1 * inv; he[k] = 1.f;
        }
        float2 xd = make_float2(0.f, 0.f);
        if (n < N) xd = ((const float2*)x)[n];
        xdx[k] = xd.x; xdy[k] = xd.y;
    }

    float acc[2][8];
#pragma unroll
    for (int k = 0; k < 2; ++k)
#pragma unroll
        for (int i = 0; i < 8; ++i) acc[k][i] = 0.f;

#pragma unroll 1
    for (int j = 0; j < 8; ++j) {
        int ci = g + 8 * j;  // float4 index; channels 4*ci..4*ci+3
        float4 hk[2];
        {
            float4 w0 = ((const float4*)sW[0])[ci];
            float4 w1 = ((const float4*)sW[1])[ci];
            float4 w2 = ((const float4*)sW[2])[ci];
            float4 w3 = ((const float4*)sW[3])[ci];
            float4 w4 = ((const float4*)sW[4])[ci];
            float4 w5 = ((const float4*)sW[5])[ci];
#pragma unroll
            for (int k = 0; k < 2; ++k) {
                hk[k].x = fmaxf(a0[k]*w0.x + a1[k]*w1.x + xdx[k]*w2.x + xdy[k]*w3.x + he[k]*w4.x + w5.x, 0.f);
                hk[k].y = fmaxf(a0[k]*w0.y + a1[k]*w1.y + xdx[k]*w2.y + xdy[k]*w3.y + he[k]*w4.y + w5.y, 0.f);
                hk[k].z = fmaxf(a0[k]*w0.z + a1[k]*w1.z + xdx[k]*w2.z + xdy[k]*w3.z + he[k]*w4.z + w5.z, 0.f);
                hk[k].w = fmaxf(a0[k]*w0.w + a1[k]*w1.w + xdx[k]*w2.w + xdy[k]*w3.w + he[k]*w4.w + w5.w, 0.f);
            }
        }
#pragma unroll
        for (int i = 0; i < 8; ++i) {
            float4 u = ((const float4*)sW[6 + i])[ci];
#pragma unroll
            for (int k = 0; k < 2; ++k)
                acc[k][i] += hk[k].x*u.x + hk[k].y*u.y + hk[k].z*u.z + hk[k].w*u.w;
        }
    }
    // width-8 reduce (all lanes end with totals)
#pragma unroll
    for (int k = 0; k < 2; ++k)
#pragma unroll
        for (int i = 0; i < 8; ++i) {
#pragma unroll
            for (int m = 1; m < 8; m <<= 1)
                acc[k][i] += __shfl_xor(acc[k][i], m);
        }
    if (g < 2) {
        int n = nb + g;
        if (n < N) {
            ((float2*)q2)[n]  = make_float2(acc[g][0] + bq2[0], acc[g][1] + bq2[1]);
            kv2[n] = make_float4(acc[g][2] + bk2[0], acc[g][3] + bk2[1],
                                 acc[g][4] + bv2[0], acc[g][5] + bv2[1]);
            ((float2*)hs2)[n] = make_float2(acc[g][6] + bs2[0], acc[g][7] + bs2[1]);
        }
    }
}

// Layer-2 edge reduce (sliced), partials out.
__global__ __launch_bounds__(256) void l2r_k(
        const float* __restrict__ q2, const float4* __restrict__ kv2,
        const int* __restrict__ recs, const int* __restrict__ cnt,
        float* __restrict__ part, int N) {
    __shared__ float qx[R_DSTS], qy[R_DSTS];
    __shared__ float ac[3 * R_DSTS];
    int t = threadIdx.x;
    int bs = blockIdx.x;
    int b = bs >> 2;
    int sl = bs & 3;
    int nbase = b << R_LOG2;
    int rem = N - nbase; if (rem > R_DSTS) rem = R_DSTS;

    ac[t] = 0.f; ac[256 + t] = 0.f; ac[512 + t] = 0.f;
    if (t < rem) {
        float2 q = ((const float2*)q2)[nbase + t];
        qx[t] = q.x * RSQRT2;
        qy[t] = q.y * RSQRT2;
    }
    __syncthreads();

    int cb = cnt[b]; if (cb > CAPB) cb = CAPB;
    int len = (cb + S_SLICES - 1) / S_SLICES;
    int lo = sl * len;
    int hi = lo + len; if (hi > cb) hi = cb;
    const int* rb = recs + (size_t)b * CAPB;
    for (int i = lo + t; i < hi; i += 256) {
        int rec = rb[i];
        int s = rec & 0x1FFFF;
        int dl = (rec >> 17) & (R_DSTS - 1);
        float4 kv = kv2[s];
        float w = __expf(qx[dl] * kv.x + qy[dl] * kv.y);
        atomicAdd(&ac[dl], w);
        atomicAdd(&ac[256 + dl], w * kv.z);
        atomicAdd(&ac[512 + dl], w * kv.w);
    }
    __syncthreads();

    float* dp = part + (size_t)bs * (3 * R_DSTS);
    dp[t] = ac[t];
    dp[256 + t] = ac[256 + t];
    dp[512 + t] = ac[512 + t];
}

// Output: 8-lane group per node reduces layer-2 slice partials (width-4),
// then skip + closed-form 2-class log_softmax.
__global__ __launch_bounds__(256) void out2x_k(
        const float* __restrict__ part, const float* __restrict__ hs2,
        float* __restrict__ out, int N) {
    int t = threadIdx.x;
    int g = t & 7;
    int n = blockIdx.x * 32 + (t >> 3);
    if (n >= N) return;
    int b = n >> R_LOG2, idx = n & (R_DSTS - 1);

    const float* pp = part + ((size_t)(b * S_SLICES + (g & 3))) * (3 * R_DSTS) + idx;
    float s = pp[0], sv0 = pp[256], sv1 = pp[512];
#pragma unroll
    for (int m = 1; m < 4; m <<= 1) {
        s   += __shfl_xor(s, m);
        sv0 += __shfl_xor(sv0, m);
        sv1 += __shfl_xor(sv1, m);
    }
    if (g != 0) return;

    float g0 = 0.f, g1 = 0.f;
    if (s > 0.f) {
        float inv = 1.0f / s;
        g0 = sv0 * inv; g1 = sv1 * inv;
    }
    float2 hs = ((const float2*)hs2)[n];
    float o0 = g0 + hs.x;
    float o1 = g1 + hs.y;
    float mx = fmaxf(o0, o1), mn = fminf(o0, o1);
    float lse = mx + log1pf(__expf(mn - mx));
    ((float2*)out)[n] = make_float2(o0 - lse, o1 - lse);
}

extern "C" void kernel_launch(void* const* d_in, const int* in_sizes, int n_in,
                              void* d_out, int out_size, void* d_ws, size_t ws_size,
                              hipStream_t stream) {
    const float* x   = (const float*)d_in[0];
    const int*   ei  = (const int*)d_in[1];
    const float* Wq1 = (const float*)d_in[2];
    const float* bq1 = (const float*)d_in[3];
    const float* Wk1 = (const float*)d_in[4];
    const float* bk1 = (const float*)d_in[5];
    const float* Wv1 = (const float*)d_in[6];
    const float* bv1 = (const float*)d_in[7];
    const float* Ws1 = (const float*)d_in[8];
    const float* bs1 = (const float*)d_in[9];
    const float* Wq2 = (const float*)d_in[10];
    const float* bq2 = (const float*)d_in[11];
    const float* Wk2 = (const float*)d_in[12];
    const float* bk2 = (const float*)d_in[13];
    const float* Wv2 = (const float*)d_in[14];
    const float* bv2 = (const float*)d_in[15];
    const float* Ws2 = (const float*)d_in[16];
    const float* bs2 = (const float*)d_in[17];

    const int N = in_sizes[0] / 2;
    const int E = in_sizes[1] / 2;
    const int* src = ei;
    const int* dst = ei + E;

    const int NB   = (N + R_DSTS - 1) >> R_LOG2;     // 391
    const int NBlk = (E + BE - 1) / BE;              // 391

    // workspace layout (4-byte units)
    float* ws = (float*)d_ws;
    size_t off = 0;
    int*   cnt   = (int*)(ws + off);         off += NB;
    int*   recs  = (int*)(ws + off);         off += (size_t)NB * CAPB;
    off = (off + 3) & ~(size_t)3;            // 16B align
    float* part  = ws + off;                 off += (size_t)NB * S_SLICES * 3 * R_DSTS;
    float4* kv2  = (float4*)(ws + off);      off += 4 * (size_t)N;
    float* q2    = ws + off;                 off += 2 * (size_t)N;
    float* hs2   = ws + off;                 off += 2 * (size_t)N;

    const int gP  = (N + 63) / 64;     // proj: 64 nodes/block
    const int gO  = (N + 31) / 32;     // out2x: 32 nodes/block

    hipMemsetAsync(cnt, 0, NB * sizeof(int), stream);
    scatter1_k<<<NBlk, 1024, 0, stream>>>(src, dst, cnt, recs, NB, E);
    l1r_k<<<NB * S_SLICES, 256, 0, stream>>>(x, Wq1, bq1, Wk1, bk1,
                                             recs, cnt, part, N);
    proj_k<<<gP, 256, 0, stream>>>(x, part, Wv1, bv1, Ws1, bs1,
                                   Wq2, bq2, Wk2, bk2, Wv2, bv2, Ws2, bs2,
                                   q2, kv2, hs2, N);
    l2r_k<<<NB * S_SLICES, 256, 0, stream>>>(q2, kv2, recs, cnt, part, N);
    out2x_k<<<gO, 256, 0, stream>>>(part, hs2, (float*)d_out, N);
}